// Round 3
// baseline (181.409 us; speedup 1.0000x reference)
//
#include <hip/hip_runtime.h>
#include <math.h>

// Problem constants (from reference): B=2, L=1024, D=256, P=32
#define B_ 2
#define L_ 1024
#define D_ 256
#define P_ 32
#define NROW (B_*L_)          // 2048 flattened (b,l) rows
#define ROWS 16               // rows per block in k_proj
#define C_ 16                 // L chunks for the scan
#define CL_ (L_/C_)           // 64 positions per chunk

// ---------------------------------------------------------------------------
// Kernel 1: fused projections.
//   values[r,d] = x[r,:] @ W_val[:,d] + b_val[d]        (if wrVal)
//   phases[r,p] = tanh(x[r,:] @ W_phase[:,p] + b) * pi  (always, to phasesPtr)
//   phasor out: mode 0 -> float2 (cos,sin); mode 1 -> float cos; mode 2 -> none
// All mode/flag args are host constants -> wave-uniform branches.
// ---------------------------------------------------------------------------
__global__ __launch_bounds__(256) void k_proj(
    const float* __restrict__ x, const float* __restrict__ Wp,
    const float* __restrict__ bp, const float* __restrict__ Wv,
    const float* __restrict__ bv, float* __restrict__ values, int wrVal,
    float* __restrict__ phases_out, float* __restrict__ phasor_out,
    int phasorMode)
{
    __shared__ float xs[ROWS][D_ + 4];
    const int row0 = blockIdx.x * ROWS;
    const int tid  = threadIdx.x;

    const float4* xg4 = (const float4*)(x + (size_t)row0 * D_);
    for (int i = tid; i < ROWS * (D_/4); i += 256) {
        int r = i >> 6, c4 = i & 63;               // D_/4 == 64
        ((float4*)&xs[r][0])[c4] = xg4[r * (D_/4) + c4];
    }
    __syncthreads();

    if (wrVal) {
        float acc[ROWS];
        #pragma unroll
        for (int r = 0; r < ROWS; ++r) acc[r] = 0.f;
        for (int k = 0; k < D_; ++k) {
            float w = Wv[k * D_ + tid];            // coalesced across lanes
            #pragma unroll
            for (int r = 0; r < ROWS; ++r) acc[r] += xs[r][k] * w; // LDS bcast
        }
        const float bvd = bv[tid];
        #pragma unroll
        for (int r = 0; r < ROWS; ++r)
            values[(size_t)(row0 + r) * D_ + tid] = acc[r] + bvd;
    }

    // phase GEMM: thread owns (p = tid&31, rows rr and rr+8)
    const int p  = tid & (P_ - 1);
    const int rr = tid >> 5;                       // 0..7
    float a0 = 0.f, a1 = 0.f;
    for (int k = 0; k < D_; ++k) {
        float w = Wp[k * P_ + p];
        a0 += xs[rr][k] * w;
        a1 += xs[rr + 8][k] * w;
    }
    const float bpp = bp[p];
    const float PIF = 3.14159265358979323846f;
    float ph0 = tanhf(a0 + bpp) * PIF;
    float ph1 = tanhf(a1 + bpp) * PIF;
    const int idx0 = (row0 + rr) * P_ + p;
    const int idx1 = (row0 + rr + 8) * P_ + p;
    phases_out[idx0] = ph0;
    phases_out[idx1] = ph1;
    if (phasorMode == 0) {
        float s0, c0, s1, c1;
        sincosf(ph0, &s0, &c0);
        sincosf(ph1, &s1, &c1);
        ((float2*)phasor_out)[idx0] = make_float2(c0, s0);
        ((float2*)phasor_out)[idx1] = make_float2(c1, s1);
    } else if (phasorMode == 1) {
        phasor_out[idx0] = cosf(ph0);
        phasor_out[idx1] = cosf(ph1);
    }
}

// ---------------------------------------------------------------------------
// Kernel 2 (path A): per-chunk partials S[b,p,c,:] = sum_{l in c} phasor*v.
// Phasor recomputed from phases (sincosf) — works in every output mode.
// ---------------------------------------------------------------------------
__global__ __launch_bounds__(128) void k_partial(
    const float* __restrict__ values, const float* __restrict__ phases,
    float4* __restrict__ S4)
{
    const int blk = blockIdx.x;                  // b*P_*C_ + p*C_ + c
    const int c = blk & (C_ - 1);
    const int p = (blk >> 4) & (P_ - 1);
    const int b = blk >> 9;
    const int tid = threadIdx.x;                 // 0..127
    const int l0 = c * CL_;

    const float2* v2 = (const float2*)(values + (size_t)(b * L_ + l0) * D_);
    float4 acc = make_float4(0.f, 0.f, 0.f, 0.f);
    for (int i = 0; i < CL_; ++i) {
        const int l = l0 + i;
        float ph = phases[(b * L_ + l) * P_ + p];    // same-addr broadcast
        float s, cs;
        sincosf(ph, &s, &cs);
        float2 v = v2[i * (D_/2) + tid];             // coalesced 8B/lane
        acc.x += cs * v.x;
        acc.y += s  * v.x;
        acc.z += cs * v.y;
        acc.w += s  * v.y;
    }
    S4[((b * P_ + p) * C_ + c) * (D_/2) + tid] = acc;
}

// ---------------------------------------------------------------------------
// Kernel 3 (path A): scan with carry from S4.
// mode 0: float4 (re0,im0,re1,im1) interleaved complex store (16B/lane)
// mode 1: float2 (re0,re1) real-part store (8B/lane)
// ---------------------------------------------------------------------------
__global__ __launch_bounds__(128) void k_scan(
    const float* __restrict__ values, const float* __restrict__ phases,
    const float4* __restrict__ S4, float* __restrict__ mem, int mode)
{
    const int blk = blockIdx.x;
    const int c = blk & (C_ - 1);
    const int p = (blk >> 4) & (P_ - 1);
    const int b = blk >> 9;
    const int tid = threadIdx.x;
    const int l0 = c * CL_;

    float4 carry = make_float4(0.f, 0.f, 0.f, 0.f);
    const float4* Sbase = S4 + (size_t)(b * P_ + p) * C_ * (D_/2) + tid;
    for (int cc = 0; cc < c; ++cc) {
        float4 s = Sbase[cc * (D_/2)];
        carry.x += s.x; carry.y += s.y; carry.z += s.z; carry.w += s.w;
    }

    const float2* v2 = (const float2*)(values + (size_t)(b * L_ + l0) * D_);
    for (int i = 0; i < CL_; ++i) {
        const int l = l0 + i;
        float ph = phases[(b * L_ + l) * P_ + p];
        float s, cs;
        sincosf(ph, &s, &cs);
        float2 v = v2[i * (D_/2) + tid];
        carry.x += cs * v.x;
        carry.y += s  * v.x;
        carry.z += cs * v.y;
        carry.w += s  * v.y;
        const size_t rowIdx = (size_t)(b * L_ + l) * P_ + p;
        if (mode == 0) {
            ((float4*)mem)[rowIdx * (D_/2) + tid] = carry;
        } else {
            ((float2*)mem)[rowIdx * (D_/2) + tid] = make_float2(carry.x, carry.z);
        }
    }
}

// ---------------------------------------------------------------------------
// Kernel 3' (path B): carry recomputed from values/phases (L2-resident).
// ---------------------------------------------------------------------------
__global__ __launch_bounds__(128) void k_scan_rc(
    const float* __restrict__ values, const float* __restrict__ phases,
    float* __restrict__ mem, int mode)
{
    const int blk = blockIdx.x;
    const int c = blk & (C_ - 1);
    const int p = (blk >> 4) & (P_ - 1);
    const int b = blk >> 9;
    const int tid = threadIdx.x;
    const int l0 = c * CL_;

    const float2* vb = (const float2*)(values + (size_t)b * L_ * D_);
    float4 carry = make_float4(0.f, 0.f, 0.f, 0.f);
    for (int l = 0; l < l0; ++l) {
        float ph = phases[(b * L_ + l) * P_ + p];
        float s, cs;
        sincosf(ph, &s, &cs);
        float2 v = vb[l * (D_/2) + tid];
        carry.x += cs * v.x; carry.y += s * v.x;
        carry.z += cs * v.y; carry.w += s * v.y;
    }
    for (int i = 0; i < CL_; ++i) {
        const int l = l0 + i;
        float ph = phases[(b * L_ + l) * P_ + p];
        float s, cs;
        sincosf(ph, &s, &cs);
        float2 v = vb[l * (D_/2) + tid];
        carry.x += cs * v.x; carry.y += s * v.x;
        carry.z += cs * v.y; carry.w += s * v.y;
        const size_t rowIdx = (size_t)(b * L_ + l) * P_ + p;
        if (mode == 0) {
            ((float4*)mem)[rowIdx * (D_/2) + tid] = carry;
        } else {
            ((float2*)mem)[rowIdx * (D_/2) + tid] = make_float2(carry.x, carry.z);
        }
    }
}

// ---------------------------------------------------------------------------
// Path C parachute (tiny ws): block per (b,p), 256 threads, value GEMM
// recomputed in 32-row tiles, serial scan. Phasor from phases array.
// ---------------------------------------------------------------------------
#define TL_ 32
__global__ __launch_bounds__(256) void k_slow(
    const float* __restrict__ x, const float* __restrict__ Wv,
    const float* __restrict__ bv, const float* __restrict__ phases,
    float* __restrict__ mem, int mode)
{
    const int b = blockIdx.x >> 5;
    const int p = blockIdx.x & (P_ - 1);
    const int tid = threadIdx.x;                 // owns output dim d = tid
    __shared__ float xs[TL_][D_];                // 32 KB

    float2 carry = make_float2(0.f, 0.f);
    const float bvd = bv[tid];
    for (int lt = 0; lt < L_; lt += TL_) {
        __syncthreads();
        const float4* xg4 = (const float4*)(x + ((size_t)b * L_ + lt) * D_);
        for (int i = tid; i < TL_ * (D_/4); i += 256)
            ((float4*)&xs[0][0])[i] = xg4[i];
        __syncthreads();

        float acc[TL_];
        #pragma unroll
        for (int r = 0; r < TL_; ++r) acc[r] = 0.f;
        for (int k = 0; k < D_; ++k) {
            float w = Wv[k * D_ + tid];
            #pragma unroll
            for (int r = 0; r < TL_; ++r) acc[r] += xs[r][k] * w;
        }
        for (int r = 0; r < TL_; ++r) {
            int l = lt + r;
            float v = acc[r] + bvd;
            float ph = phases[(b * L_ + l) * P_ + p];
            float s, cs;
            sincosf(ph, &s, &cs);
            carry.x += cs * v;
            carry.y += s * v;
            const size_t rowIdx = (size_t)(b * L_ + l) * P_ + p;
            if (mode == 0) ((float2*)mem)[rowIdx * D_ + tid] = carry;
            else           mem[rowIdx * D_ + tid] = carry.x;
        }
    }
}

extern "C" void kernel_launch(void* const* d_in, const int* in_sizes, int n_in,
                              void* d_out, int out_size, void* d_ws, size_t ws_size,
                              hipStream_t stream) {
    const float* x  = (const float*)d_in[0];
    const float* Wp = (const float*)d_in[1];
    const float* bp = (const float*)d_in[2];
    const float* Wv = (const float*)d_in[3];
    const float* bv = (const float*)d_in[4];
    float* out = (float*)d_out;

    const size_t nMemF = (size_t)2 * B_ * L_ * P_ * D_;  // 33554432 (interleaved)
    const size_t nMemR = (size_t)B_ * L_ * P_ * D_;      // 16777216 (real only)
    const size_t nPh   = (size_t)B_ * L_ * P_;           // 65536

    // Output layout mode, chosen by out_size (constant per session).
    int mode; size_t memFloats;
    if ((size_t)out_size >= nMemF + 3 * nPh) { mode = 0; memFloats = nMemF; }
    else                                     { mode = 1; memFloats = nMemR; }
    const bool memFits      = (size_t)out_size >= memFloats;
    const bool phasesInOut  = (size_t)out_size >= memFloats + nPh;
    const bool phasorsInOut =
        (size_t)out_size >= memFloats + nPh + (mode == 0 ? 2 * nPh : nPh);

    // ws layout: values | phasesWs | S4
    const size_t valCnt = (size_t)B_ * L_ * D_;          // 524288 floats (2 MB)
    const size_t valB   = valCnt * sizeof(float);
    const size_t phB    = nPh * sizeof(float);           // 256 KB
    const size_t s4B    = (size_t)B_ * P_ * C_ * (D_/2) * sizeof(float4); // 2 MB
    float*  values   = (float*)d_ws;
    float*  phasesWs = (float*)((char*)d_ws + valB);
    float4* S4       = (float4*)((char*)d_ws + valB + phB);

    float* phasesPtr = nullptr;
    if (phasesInOut)                       phasesPtr = out + memFloats;
    else if (ws_size >= valB + phB)        phasesPtr = phasesWs;
    else if (ws_size >= phB)               phasesPtr = (float*)d_ws; // path C only
    if (phasesPtr == nullptr) return;      // cannot proceed safely (unreachable in practice)

    float* phasorPtr = phasorsInOut ? (out + memFloats + nPh) : nullptr;
    const int phasorMode = phasorsInOut ? mode : 2;

    const bool pathA = ws_size >= valB + phB + s4B;      // 4.25 MB
    const bool pathB = ws_size >= valB + phB;            // 2.25 MB
    const int  wrVal = (pathA || pathB) ? 1 : 0;

    k_proj<<<NROW / ROWS, 256, 0, stream>>>(x, Wp, bp, Wv, bv,
                                            values, wrVal,
                                            phasesPtr, phasorPtr, phasorMode);
    if (!memFits) return;                                // nothing else fits

    if (pathA) {
        k_partial<<<B_ * P_ * C_, 128, 0, stream>>>(values, phasesPtr, S4);
        k_scan<<<B_ * P_ * C_, 128, 0, stream>>>(values, phasesPtr, S4, out, mode);
    } else if (pathB) {
        k_scan_rc<<<B_ * P_ * C_, 128, 0, stream>>>(values, phasesPtr, out, mode);
    } else {
        k_slow<<<B_ * P_, 256, 0, stream>>>(x, Wv, bv, phasesPtr, out, mode);
    }
}

// Round 5
// 118.093 us; speedup vs baseline: 1.5362x; 1.5362x over previous
//
#include <hip/hip_runtime.h>
#include <math.h>

// Problem constants (from reference): B=2, L=1024, D=256, P=32
#define B_ 2
#define L_ 1024
#define D_ 256
#define P_ 32
#define NROW (B_*L_)          // 2048 flattened (b,l) rows
#define C_ 16                 // L chunks for the scan
#define CL_ (L_/C_)           // 64 positions per chunk
#define PIF 3.14159265358979323846f

// Native clang vector types — required by __builtin_nontemporal_store
typedef float nvf4 __attribute__((ext_vector_type(4)));
typedef float nvf2 __attribute__((ext_vector_type(2)));

// ---------------------------------------------------------------------------
// Merged projection kernel, 768 blocks x 256 threads.
//  blocks [0, 512): values GEMM. Block = 4 rows; thread = (row r=tid>>6,
//    4 cols via float4). Wv float4 loads are 1KB/wave fully coalesced; x
//    comes from LDS with wave-uniform address (free broadcast).
//  blocks [512, 768): phase GEMM. Block = 8 rows x 32 p; thread owns one
//    (row, p): tanh -> phases, sincos -> phasors (interleaved complex).
// phasorMode: 0 = float2 (cos,sin), 1 = cos only, 2 = skip (host constant).
// ---------------------------------------------------------------------------
__global__ __launch_bounds__(256) void k_proj2(
    const float* __restrict__ x, const float* __restrict__ Wp,
    const float* __restrict__ bp, const float* __restrict__ Wv,
    const float* __restrict__ bv, float* __restrict__ values,
    float* __restrict__ phases_out, float* __restrict__ phasor_out,
    int phasorMode)
{
    __shared__ float xs[8 * D_];                 // 8 KB
    const int tid = threadIdx.x;

    if (blockIdx.x < NROW / 4) {
        // ---- values: rows [row0, row0+4) ----
        const int row0 = blockIdx.x * 4;
        const float4* xg4 = (const float4*)(x + (size_t)row0 * D_);
        ((float4*)xs)[tid] = xg4[tid];           // 4*256 floats = 256 float4
        __syncthreads();

        const int c4 = tid & 63;                 // float4 column group
        const int r  = tid >> 6;                 // 0..3, wave-uniform
        const float* xr = xs + r * D_;
        const float4* Wv4 = (const float4*)Wv;
        float4 acc = make_float4(0.f, 0.f, 0.f, 0.f);
        #pragma unroll 8
        for (int k = 0; k < D_; ++k) {
            float4 w = Wv4[k * 64 + c4];         // coalesced 1KB/wave
            float xv = xr[k];                    // LDS broadcast
            acc.x += xv * w.x; acc.y += xv * w.y;
            acc.z += xv * w.z; acc.w += xv * w.w;
        }
        const float4 b4 = ((const float4*)bv)[c4];
        acc.x += b4.x; acc.y += b4.y; acc.z += b4.z; acc.w += b4.w;
        ((float4*)values)[(size_t)(row0 + r) * 64 + c4] = acc;
    } else {
        // ---- phases/phasors: rows [row0, row0+8) ----
        const int row0 = (blockIdx.x - NROW / 4) * 8;
        const float4* xg4 = (const float4*)(x + (size_t)row0 * D_);
        ((float4*)xs)[tid]       = xg4[tid];     // 8*256 floats = 512 float4
        ((float4*)xs)[tid + 256] = xg4[tid + 256];
        __syncthreads();

        const int p  = tid & (P_ - 1);
        const int rr = tid >> 5;                 // 0..7
        const float* xr = xs + rr * D_;
        float a = 0.f;
        #pragma unroll 8
        for (int k = 0; k < D_; ++k)
            a += xr[k] * Wp[k * P_ + p];         // 128B bcast per wave
        float ph = tanhf(a + bp[p]) * PIF;
        const int idx = (row0 + rr) * P_ + p;
        phases_out[idx] = ph;
        if (phasorMode == 0) {
            float s, c;
            sincosf(ph, &s, &c);
            ((float2*)phasor_out)[idx] = make_float2(c, s);
        } else if (phasorMode == 1) {
            phasor_out[idx] = cosf(ph);
        }
    }
}

// ---------------------------------------------------------------------------
// Chunk partials S[b,p,c,:] = sum_{l in chunk} phasor * v.
// Phasors computed ONCE per chunk (64 HW sin/cos) into LDS, then broadcast.
// ---------------------------------------------------------------------------
__global__ __launch_bounds__(128) void k_partial(
    const float* __restrict__ values, const float* __restrict__ phases,
    float4* __restrict__ S4)
{
    const int blk = blockIdx.x;                  // b*P_*C_ + p*C_ + c
    const int c = blk & (C_ - 1);
    const int p = (blk >> 4) & (P_ - 1);
    const int b = blk >> 9;
    const int tid = threadIdx.x;                 // 0..127
    const int l0 = c * CL_;

    __shared__ float2 pc[CL_];
    if (tid < CL_) {
        float ph = phases[(b * L_ + l0 + tid) * P_ + p];
        pc[tid] = make_float2(__cosf(ph), __sinf(ph));
    }
    __syncthreads();

    const float2* v2 = (const float2*)(values + (size_t)(b * L_ + l0) * D_);
    float4 acc = make_float4(0.f, 0.f, 0.f, 0.f);
    #pragma unroll 4
    for (int i = 0; i < CL_; ++i) {
        float2 ph = pc[i];                       // same-addr LDS broadcast
        float2 v  = v2[i * (D_/2) + tid];        // coalesced 8B/lane (L2)
        acc.x += ph.x * v.x;
        acc.y += ph.y * v.x;
        acc.z += ph.x * v.y;
        acc.w += ph.y * v.y;
    }
    S4[((b * P_ + p) * C_ + c) * (D_/2) + tid] = acc;
}

// ---------------------------------------------------------------------------
// Scan: carry = sum of preceding chunk partials, then 64-step running sum.
// mode 0: float4 interleaved complex store; mode 1: float2 real-part store.
// Non-temporal stores — the 134 MB output is write-once, bypass L2.
// ---------------------------------------------------------------------------
__global__ __launch_bounds__(128) void k_scan(
    const float* __restrict__ values, const float* __restrict__ phases,
    const float4* __restrict__ S4, float* __restrict__ mem, int mode)
{
    const int blk = blockIdx.x;
    const int c = blk & (C_ - 1);
    const int p = (blk >> 4) & (P_ - 1);
    const int b = blk >> 9;
    const int tid = threadIdx.x;
    const int l0 = c * CL_;

    __shared__ float2 pc[CL_];
    if (tid < CL_) {
        float ph = phases[(b * L_ + l0 + tid) * P_ + p];
        pc[tid] = make_float2(__cosf(ph), __sinf(ph));
    }

    float4 carry = make_float4(0.f, 0.f, 0.f, 0.f);
    const float4* Sbase = S4 + (size_t)(b * P_ + p) * C_ * (D_/2) + tid;
    for (int cc = 0; cc < c; ++cc) {             // ≤15 independent loads
        float4 s = Sbase[cc * (D_/2)];
        carry.x += s.x; carry.y += s.y; carry.z += s.z; carry.w += s.w;
    }
    __syncthreads();

    const float2* v2 = (const float2*)(values + (size_t)(b * L_ + l0) * D_);
    #pragma unroll 4
    for (int i = 0; i < CL_; ++i) {
        float2 ph = pc[i];
        float2 v  = v2[i * (D_/2) + tid];
        carry.x += ph.x * v.x;
        carry.y += ph.y * v.x;
        carry.z += ph.x * v.y;
        carry.w += ph.y * v.y;
        const size_t rowIdx = (size_t)(b * L_ + l0 + i) * P_ + p;
        if (mode == 0) {
            nvf4 cv = { carry.x, carry.y, carry.z, carry.w };
            __builtin_nontemporal_store(cv, (nvf4*)mem + rowIdx * (D_/2) + tid);
        } else {
            nvf2 cv = { carry.x, carry.z };
            __builtin_nontemporal_store(cv, (nvf2*)mem + rowIdx * (D_/2) + tid);
        }
    }
}

// ---------------------------------------------------------------------------
// Path B parachute (small ws): carry recomputed from values/phases via L2.
// ---------------------------------------------------------------------------
__global__ __launch_bounds__(128) void k_scan_rc(
    const float* __restrict__ values, const float* __restrict__ phases,
    float* __restrict__ mem, int mode)
{
    const int blk = blockIdx.x;
    const int c = blk & (C_ - 1);
    const int p = (blk >> 4) & (P_ - 1);
    const int b = blk >> 9;
    const int tid = threadIdx.x;
    const int l0 = c * CL_;

    const float2* vb = (const float2*)(values + (size_t)b * L_ * D_);
    float4 carry = make_float4(0.f, 0.f, 0.f, 0.f);
    for (int l = 0; l < l0; ++l) {
        float ph = phases[(b * L_ + l) * P_ + p];
        float s = __sinf(ph), cs = __cosf(ph);
        float2 v = vb[l * (D_/2) + tid];
        carry.x += cs * v.x; carry.y += s * v.x;
        carry.z += cs * v.y; carry.w += s * v.y;
    }
    for (int i = 0; i < CL_; ++i) {
        const int l = l0 + i;
        float ph = phases[(b * L_ + l) * P_ + p];
        float s = __sinf(ph), cs = __cosf(ph);
        float2 v = vb[l * (D_/2) + tid];
        carry.x += cs * v.x; carry.y += s * v.x;
        carry.z += cs * v.y; carry.w += s * v.y;
        const size_t rowIdx = (size_t)(b * L_ + l) * P_ + p;
        if (mode == 0) ((float4*)mem)[rowIdx * (D_/2) + tid] = carry;
        else ((float2*)mem)[rowIdx * (D_/2) + tid] = make_float2(carry.x, carry.z);
    }
}

extern "C" void kernel_launch(void* const* d_in, const int* in_sizes, int n_in,
                              void* d_out, int out_size, void* d_ws, size_t ws_size,
                              hipStream_t stream) {
    const float* x  = (const float*)d_in[0];
    const float* Wp = (const float*)d_in[1];
    const float* bp = (const float*)d_in[2];
    const float* Wv = (const float*)d_in[3];
    const float* bv = (const float*)d_in[4];
    float* out = (float*)d_out;

    const size_t nMemF = (size_t)2 * B_ * L_ * P_ * D_;  // 33554432 (interleaved)
    const size_t nMemR = (size_t)B_ * L_ * P_ * D_;      // 16777216 (real only)
    const size_t nPh   = (size_t)B_ * L_ * P_;           // 65536

    // Output layout mode by out_size (constant per session; round-3 verified
    // mode 0: memory interleaved complex | phases | phasors interleaved).
    int mode; size_t memFloats;
    if ((size_t)out_size >= nMemF + 3 * nPh) { mode = 0; memFloats = nMemF; }
    else                                     { mode = 1; memFloats = nMemR; }
    const bool memFits      = (size_t)out_size >= memFloats;
    const bool phasesInOut  = (size_t)out_size >= memFloats + nPh;
    const bool phasorsInOut =
        (size_t)out_size >= memFloats + nPh + (mode == 0 ? 2 * nPh : nPh);

    // ws layout: values | phasesWs | S4
    const size_t valB = (size_t)B_ * L_ * D_ * sizeof(float);                // 2 MB
    const size_t phB  = nPh * sizeof(float);                                 // 256 KB
    const size_t s4B  = (size_t)B_ * P_ * C_ * (D_/2) * sizeof(float4);      // 2 MB
    float*  values   = (float*)d_ws;
    float*  phasesWs = (float*)((char*)d_ws + valB);
    float4* S4       = (float4*)((char*)d_ws + valB + phB);

    float* phasesPtr = phasesInOut ? (out + memFloats)
                     : (ws_size >= valB + phB ? phasesWs : nullptr);
    if (phasesPtr == nullptr) return;            // unreachable (ws verified >= 4.25MB)

    float* phasorPtr = phasorsInOut ? (out + memFloats + nPh) : nullptr;
    const int phasorMode = phasorsInOut ? mode : 2;

    k_proj2<<<NROW / 4 + NROW / 8, 256, 0, stream>>>(
        x, Wp, bp, Wv, bv, values, phasesPtr, phasorPtr, phasorMode);
    if (!memFits) return;

    if (ws_size >= valB + phB + s4B) {
        k_partial<<<B_ * P_ * C_, 128, 0, stream>>>(values, phasesPtr, S4);
        k_scan<<<B_ * P_ * C_, 128, 0, stream>>>(values, phasesPtr, S4, out, mode);
    } else {
        k_scan_rc<<<B_ * P_ * C_, 128, 0, stream>>>(values, phasesPtr, out, mode);
    }
}

// Round 6
// 111.568 us; speedup vs baseline: 1.6260x; 1.0585x over previous
//
#include <hip/hip_runtime.h>
#include <math.h>

// Problem constants (from reference): B=2, L=1024, D=256, P=32
#define B_ 2
#define L_ 1024
#define D_ 256
#define P_ 32
#define NROW (B_*L_)          // 2048 flattened (b,l) rows
#define C_ 16                 // L chunks for the scan
#define CL_ (L_/C_)           // 64 positions per chunk
#define PIF 3.14159265358979323846f

// Native clang vector types — required by __builtin_nontemporal_store
typedef float nvf4 __attribute__((ext_vector_type(4)));
typedef float nvf2 __attribute__((ext_vector_type(2)));

// ---------------------------------------------------------------------------
// Projection kernel, 768 blocks x 256 threads.
//  blocks [0, 512): values GEMM, 4 rows/block, K-SPLIT: quarter-wave q owns
//    k in [64q, 64q+64) so the block streams Wv exactly ONCE (was 4x),
//    partial accs reduced through 16 KB LDS. Wv float4 loads coalesced 1KB/wave.
//  blocks [512, 768): phase GEMM, 8 rows x 32 p; tanh -> phases,
//    sincos -> phasors (d_out) + transposed copy phasorT[(b*P+p)*L+l] (ws)
//    for coalesced access in partial/scan.
// phasorMode: 0 = float2 (cos,sin), 1 = cos only, 2 = skip. hasPT: write pcT.
// ---------------------------------------------------------------------------
__global__ __launch_bounds__(256) void k_proj3(
    const float* __restrict__ x, const float* __restrict__ Wp,
    const float* __restrict__ bp, const float* __restrict__ Wv,
    const float* __restrict__ bv, float* __restrict__ values,
    float* __restrict__ phases_out, float* __restrict__ phasor_out,
    float2* __restrict__ phasorT, int phasorMode, int hasPT)
{
    __shared__ float smem[5120];                 // 20 KB carved below
    const int tid = threadIdx.x;

    if (blockIdx.x < NROW / 4) {
        // ---- values: rows [row0, row0+4), K-split ----
        const int row0 = blockIdx.x * 4;
        float*  xsv = smem;                      // 1024 floats (4 KB)
        float4* red = (float4*)(smem + 1024);    // 1024 float4 (16 KB)

        ((float4*)xsv)[tid] = ((const float4*)(x + (size_t)row0 * D_))[tid];
        __syncthreads();

        const int q  = tid >> 6;                 // k-quarter, wave-uniform
        const int c4 = tid & 63;                 // float4 column group
        const float4* Wv4 = (const float4*)Wv;
        float4 acc[4];
        #pragma unroll
        for (int r = 0; r < 4; ++r) acc[r] = make_float4(0.f, 0.f, 0.f, 0.f);

        const int k0 = q * 64;
        #pragma unroll 4
        for (int kk = 0; kk < 64; ++kk) {
            const int k = k0 + kk;
            float4 w = Wv4[k * 64 + c4];         // coalesced 1KB/wave, Wv once/block
            #pragma unroll
            for (int r = 0; r < 4; ++r) {
                float xv = xsv[r * D_ + k];      // wave-uniform LDS broadcast
                acc[r].x += xv * w.x; acc[r].y += xv * w.y;
                acc[r].z += xv * w.z; acc[r].w += xv * w.w;
            }
        }
        #pragma unroll
        for (int r = 0; r < 4; ++r) red[(r * 4 + q) * 64 + c4] = acc[r];
        __syncthreads();

        const int r2 = tid >> 6;                 // row this thread finalizes
        float4 s0 = red[(r2 * 4 + 0) * 64 + c4];
        float4 s1 = red[(r2 * 4 + 1) * 64 + c4];
        float4 s2 = red[(r2 * 4 + 2) * 64 + c4];
        float4 s3 = red[(r2 * 4 + 3) * 64 + c4];
        const float4 b4 = ((const float4*)bv)[c4];
        float4 out;
        out.x = s0.x + s1.x + s2.x + s3.x + b4.x;
        out.y = s0.y + s1.y + s2.y + s3.y + b4.y;
        out.z = s0.z + s1.z + s2.z + s3.z + b4.z;
        out.w = s0.w + s1.w + s2.w + s3.w + b4.w;
        ((float4*)values)[(size_t)(row0 + r2) * 64 + c4] = out;
    } else {
        // ---- phases/phasors: rows [row0, row0+8) ----
        const int row0 = (blockIdx.x - NROW / 4) * 8;
        float* xs = smem;                        // 2048 floats (8 KB)
        const float4* xg4 = (const float4*)(x + (size_t)row0 * D_);
        ((float4*)xs)[tid]       = xg4[tid];
        ((float4*)xs)[tid + 256] = xg4[tid + 256];
        __syncthreads();

        const int p  = tid & (P_ - 1);
        const int rr = tid >> 5;                 // 0..7
        const float* xr = xs + rr * D_;
        float a = 0.f;
        #pragma unroll 8
        for (int k = 0; k < D_; ++k)
            a += xr[k] * Wp[k * P_ + p];         // 128B bcast per wave
        float ph = tanhf(a + bp[p]) * PIF;
        const int row = row0 + rr;
        const int idx = row * P_ + p;
        phases_out[idx] = ph;
        float s, c;
        sincosf(ph, &s, &c);
        if (phasorMode == 0) {
            ((float2*)phasor_out)[idx] = make_float2(c, s);
        } else if (phasorMode == 1) {
            phasor_out[idx] = c;
        }
        if (hasPT) {
            const int b = row >> 10, l = row & (L_ - 1);
            phasorT[(b * P_ + p) * L_ + l] = make_float2(c, s);
        }
    }
}

// ---------------------------------------------------------------------------
// Chunk partials S[b,p,c,:] = sum_{l in chunk} phasor * v.
// Phasors: coalesced 512B load from phasorT (hasPT) else strided+sincos.
// ---------------------------------------------------------------------------
__global__ __launch_bounds__(128) void k_partial(
    const float* __restrict__ values, const float* __restrict__ phases,
    const float2* __restrict__ phasorT, float4* __restrict__ S4, int hasPT)
{
    const int blk = blockIdx.x;                  // b*P_*C_ + p*C_ + c
    const int c = blk & (C_ - 1);
    const int p = (blk >> 4) & (P_ - 1);
    const int b = blk >> 9;
    const int tid = threadIdx.x;                 // 0..127
    const int l0 = c * CL_;

    __shared__ float2 pc[CL_];
    if (tid < CL_) {
        if (hasPT) {
            pc[tid] = phasorT[(b * P_ + p) * L_ + l0 + tid];
        } else {
            float ph = phases[(b * L_ + l0 + tid) * P_ + p];
            pc[tid] = make_float2(__cosf(ph), __sinf(ph));
        }
    }
    __syncthreads();

    const float2* v2 = (const float2*)(values + (size_t)(b * L_ + l0) * D_);
    float4 acc = make_float4(0.f, 0.f, 0.f, 0.f);
    #pragma unroll 8
    for (int i = 0; i < CL_; ++i) {
        float2 ph = pc[i];                       // same-addr LDS broadcast
        float2 v  = v2[i * (D_/2) + tid];        // coalesced 8B/lane (L2)
        acc.x += ph.x * v.x;
        acc.y += ph.y * v.x;
        acc.z += ph.x * v.y;
        acc.w += ph.y * v.y;
    }
    S4[((b * P_ + p) * C_ + c) * (D_/2) + tid] = acc;
}

// ---------------------------------------------------------------------------
// Scan: carry = sum of preceding chunk partials, then 64-step running sum.
// mode 0: float4 interleaved complex NT store; mode 1: float2 real-part.
// ---------------------------------------------------------------------------
__global__ __launch_bounds__(128) void k_scan(
    const float* __restrict__ values, const float* __restrict__ phases,
    const float2* __restrict__ phasorT, const float4* __restrict__ S4,
    float* __restrict__ mem, int mode, int hasPT)
{
    const int blk = blockIdx.x;
    const int c = blk & (C_ - 1);
    const int p = (blk >> 4) & (P_ - 1);
    const int b = blk >> 9;
    const int tid = threadIdx.x;
    const int l0 = c * CL_;

    __shared__ float2 pc[CL_];
    if (tid < CL_) {
        if (hasPT) {
            pc[tid] = phasorT[(b * P_ + p) * L_ + l0 + tid];
        } else {
            float ph = phases[(b * L_ + l0 + tid) * P_ + p];
            pc[tid] = make_float2(__cosf(ph), __sinf(ph));
        }
    }

    float4 carry = make_float4(0.f, 0.f, 0.f, 0.f);
    const float4* Sbase = S4 + (size_t)(b * P_ + p) * C_ * (D_/2) + tid;
    for (int cc = 0; cc < c; ++cc) {             // ≤15 independent loads
        float4 s = Sbase[cc * (D_/2)];
        carry.x += s.x; carry.y += s.y; carry.z += s.z; carry.w += s.w;
    }
    __syncthreads();

    const float2* v2 = (const float2*)(values + (size_t)(b * L_ + l0) * D_);
    #pragma unroll 8
    for (int i = 0; i < CL_; ++i) {
        float2 ph = pc[i];
        float2 v  = v2[i * (D_/2) + tid];
        carry.x += ph.x * v.x;
        carry.y += ph.y * v.x;
        carry.z += ph.x * v.y;
        carry.w += ph.y * v.y;
        const size_t rowIdx = (size_t)(b * L_ + l0 + i) * P_ + p;
        if (mode == 0) {
            nvf4 cv = { carry.x, carry.y, carry.z, carry.w };
            __builtin_nontemporal_store(cv, (nvf4*)mem + rowIdx * (D_/2) + tid);
        } else {
            nvf2 cv = { carry.x, carry.z };
            __builtin_nontemporal_store(cv, (nvf2*)mem + rowIdx * (D_/2) + tid);
        }
    }
}

// ---------------------------------------------------------------------------
// Path B parachute (small ws): carry recomputed from values/phases via L2.
// ---------------------------------------------------------------------------
__global__ __launch_bounds__(128) void k_scan_rc(
    const float* __restrict__ values, const float* __restrict__ phases,
    float* __restrict__ mem, int mode)
{
    const int blk = blockIdx.x;
    const int c = blk & (C_ - 1);
    const int p = (blk >> 4) & (P_ - 1);
    const int b = blk >> 9;
    const int tid = threadIdx.x;
    const int l0 = c * CL_;

    const float2* vb = (const float2*)(values + (size_t)b * L_ * D_);
    float4 carry = make_float4(0.f, 0.f, 0.f, 0.f);
    for (int l = 0; l < l0; ++l) {
        float ph = phases[(b * L_ + l) * P_ + p];
        float s = __sinf(ph), cs = __cosf(ph);
        float2 v = vb[l * (D_/2) + tid];
        carry.x += cs * v.x; carry.y += s * v.x;
        carry.z += cs * v.y; carry.w += s * v.y;
    }
    for (int i = 0; i < CL_; ++i) {
        const int l = l0 + i;
        float ph = phases[(b * L_ + l) * P_ + p];
        float s = __sinf(ph), cs = __cosf(ph);
        float2 v = vb[l * (D_/2) + tid];
        carry.x += cs * v.x; carry.y += s * v.x;
        carry.z += cs * v.y; carry.w += s * v.y;
        const size_t rowIdx = (size_t)(b * L_ + l) * P_ + p;
        if (mode == 0) ((float4*)mem)[rowIdx * (D_/2) + tid] = carry;
        else ((float2*)mem)[rowIdx * (D_/2) + tid] = make_float2(carry.x, carry.z);
    }
}

extern "C" void kernel_launch(void* const* d_in, const int* in_sizes, int n_in,
                              void* d_out, int out_size, void* d_ws, size_t ws_size,
                              hipStream_t stream) {
    const float* x  = (const float*)d_in[0];
    const float* Wp = (const float*)d_in[1];
    const float* bp = (const float*)d_in[2];
    const float* Wv = (const float*)d_in[3];
    const float* bv = (const float*)d_in[4];
    float* out = (float*)d_out;

    const size_t nMemF = (size_t)2 * B_ * L_ * P_ * D_;  // 33554432 (interleaved)
    const size_t nMemR = (size_t)B_ * L_ * P_ * D_;      // 16777216 (real only)
    const size_t nPh   = (size_t)B_ * L_ * P_;           // 65536

    // Output layout mode by out_size (round-3/5 verified: mode 0 —
    // memory interleaved complex | phases | phasors interleaved).
    int mode; size_t memFloats;
    if ((size_t)out_size >= nMemF + 3 * nPh) { mode = 0; memFloats = nMemF; }
    else                                     { mode = 1; memFloats = nMemR; }
    const bool memFits      = (size_t)out_size >= memFloats;
    const bool phasesInOut  = (size_t)out_size >= memFloats + nPh;
    const bool phasorsInOut =
        (size_t)out_size >= memFloats + nPh + (mode == 0 ? 2 * nPh : nPh);

    // ws layout: values | phasesWs | S4 | phasorT
    const size_t valB = (size_t)B_ * L_ * D_ * sizeof(float);                // 2 MB
    const size_t phB  = nPh * sizeof(float);                                 // 256 KB
    const size_t s4B  = (size_t)B_ * P_ * C_ * (D_/2) * sizeof(float4);      // 2 MB
    const size_t ptB  = (size_t)B_ * P_ * L_ * sizeof(float2);               // 512 KB
    float*  values   = (float*)d_ws;
    float*  phasesWs = (float*)((char*)d_ws + valB);
    float4* S4       = (float4*)((char*)d_ws + valB + phB);
    float2* phasorT  = (float2*)((char*)d_ws + valB + phB + s4B);

    float* phasesPtr = phasesInOut ? (out + memFloats)
                     : (ws_size >= valB + phB ? phasesWs : nullptr);
    if (phasesPtr == nullptr) return;            // unreachable (ws verified big enough)

    float* phasorPtr = phasorsInOut ? (out + memFloats + nPh) : nullptr;
    const int phasorMode = phasorsInOut ? mode : 2;

    const bool pathA = ws_size >= valB + phB + s4B;          // partials fit
    const int  hasPT = (pathA && ws_size >= valB + phB + s4B + ptB) ? 1 : 0;

    k_proj3<<<NROW / 4 + NROW / 8, 256, 0, stream>>>(
        x, Wp, bp, Wv, bv, values, phasesPtr, phasorPtr, phasorT,
        phasorMode, hasPT);
    if (!memFits) return;

    if (pathA) {
        k_partial<<<B_ * P_ * C_, 128, 0, stream>>>(values, phasesPtr, phasorT,
                                                    S4, hasPT);
        k_scan<<<B_ * P_ * C_, 128, 0, stream>>>(values, phasesPtr, phasorT,
                                                 S4, out, mode, hasPT);
    } else {
        k_scan_rc<<<B_ * P_ * C_, 128, 0, stream>>>(values, phasesPtr, out, mode);
    }
}